// Round 17
// baseline (85.460 us; speedup 1.0000x reference)
//
#include <hip/hip_runtime.h>
#include <cstddef>
#include <cstdint>

#define SPTS 512
#define PPS  512
#define KFPS 10
#define NMSK 128
#define HH 512
#define WW 512
#define HWPIX (HH*WW)
#define FDIM 32
#define TOPK_SEL 10
#define NMASK_TOP 5

// ---------- mask dtype handling (u8 / int32 / float32) ----------
__device__ __forceinline__ unsigned mask_val(const void* raw, long long idx, int mode) {
    if (mode == 0) return ((const unsigned char*)raw)[idx] ? 1u : 0u;
    if (mode == 1) return ((const int*)raw)[idx] ? 1u : 0u;
    return (((const float*)raw)[idx] != 0.0f) ? 1u : 0u;
}

// In-block mask dtype detection from the first 4096 bytes (L2-hot after block 0).
// u8 bool: nonzero bytes at offsets %4==1. f32 0/1: nonzero at %4∈{2,3}. int32: %4==0 only.
__device__ __forceinline__ int detect_mode(const void* raw) {
    __shared__ int s_any1, s_any23;
    if (threadIdx.x == 0) { s_any1 = 0; s_any23 = 0; }
    __syncthreads();
    if (threadIdx.x < 256) {
        uint4 w = ((const uint4*)raw)[threadIdx.x];
        unsigned b1  = (w.x >> 8 | w.y >> 8 | w.z >> 8 | w.w >> 8) & 0xFFu;
        unsigned b23 = ((w.x >> 16) | (w.y >> 16) | (w.z >> 16) | (w.w >> 16)) & 0xFFFFu;
        if (b1)  atomicOr(&s_any1, 1);
        if (b23) atomicOr(&s_any23, 1);
    }
    __syncthreads();
    return s_any1 ? 0 : (s_any23 ? 2 : 1);
}

// ---------- wave-level FPS for superpoint s (one 64-lane wave, no block barriers) ----------
__device__ __forceinline__ void fps_wave(const float* pcds, float* reps, int s, int lane) {
    const float* base = pcds + (size_t)s * PPS * 3;
    float px_[8], py_[8], pz_[8];
#pragma unroll
    for (int k = 0; k < 8; ++k) {
        int p = lane + 64 * k;
        px_[k] = base[p * 3 + 0];
        py_[k] = base[p * 3 + 1];
        pz_[k] = base[p * 3 + 2];
    }
    float ax = __shfl(px_[0], 0), ay = __shfl(py_[0], 0), az = __shfl(pz_[0], 0);
    float dist[8];
#pragma unroll
    for (int k = 0; k < 8; ++k) {
        float dx = px_[k] - ax, dy = py_[k] - ay, dz = pz_[k] - az;
        dist[k] = sqrtf(dx * dx + dy * dy + dz * dz);
    }
    if (lane == 0) {
        reps[((size_t)s * KFPS + 0) * 3 + 0] = ax;
        reps[((size_t)s * KFPS + 0) * 3 + 1] = ay;
        reps[((size_t)s * KFPS + 0) * 3 + 2] = az;
    }
    for (int kk = 1; kk < KFPS; ++kk) {
        float bv = dist[0]; int bk = 0;
#pragma unroll
        for (int k = 1; k < 8; ++k)
            if (dist[k] > bv) { bv = dist[k]; bk = k; }
        float v = bv; int pidx = lane + 64 * bk;
        // wave argmax; tie -> lower global point index (matches jnp.argmax)
#pragma unroll
        for (int off = 1; off < 64; off <<= 1) {
            float ov = __shfl_xor(v, off);
            int   op = __shfl_xor(pidx, off);
            if (ov > v || (ov == v && op < pidx)) { v = ov; pidx = op; }
        }
        int owner = pidx & 63, slot = pidx >> 6;
        float sx = px_[0], sy = py_[0], sz = pz_[0];
#pragma unroll
        for (int j = 1; j < 8; ++j)
            if (slot == j) { sx = px_[j]; sy = py_[j]; sz = pz_[j]; }
        sx = __shfl(sx, owner); sy = __shfl(sy, owner); sz = __shfl(sz, owner);
        if (lane == 0) {
            reps[((size_t)s * KFPS + kk) * 3 + 0] = sx;
            reps[((size_t)s * KFPS + kk) * 3 + 1] = sy;
            reps[((size_t)s * KFPS + kk) * 3 + 2] = sz;
        }
#pragma unroll
        for (int k = 0; k < 8; ++k) {
            float dx = px_[k] - sx, dy = py_[k] - sy, dz = pz_[k] - sz;
            float d = sqrtf(dx * dx + dy * dy + dz * dz);
            dist[k] = fminf(dist[k], d);
        }
    }
}

// ========== Node A: LINEAR ballot-bitpack (2048 blocks x 256 thr = 8192 waves) ==========
// dword path: wave streams 4096 consecutive dwords (16KB contiguous). Per 64-dword
// group: lane i reads dword base+i (256B coalesced), __ballot(v!=0) -> one uint64
// bitmap word (64 px of one mask). 8 loads in flight/wave; 32 waves/CU.
//   bitmap64[W] bit p = (raw32[W*64+p] != 0); W = wave_id*64 + group.
//   Coverage: 8192 waves x 4096 dwords = 33554432 = NMSK*HWPIX exactly.
//   Mask boundaries: HWPIX/64 = 4096 words/mask; wave span (64 words) never straddles.
// u8 path: R15-proven wide-chunk direct repack (bids 0..255), maskbits written directly.
__global__ void __launch_bounds__(256) k_bitpack(const void* raw, unsigned* maskbits,
                                                 unsigned long long* bitmap64) {
    int bid = blockIdx.x;
    int t = threadIdx.x;
    int mode = detect_mode(raw);
    if (mode == 0) {
        if (bid >= 256) return;
        int pix0 = bid * 1024 + t * 4;
        unsigned w[4][4] = {};
        const unsigned char* base = (const unsigned char*)raw + pix0;
        for (int g = 0; g < 16; ++g) {
            unsigned v[8];
#pragma unroll
            for (int j = 0; j < 8; ++j)
                v[j] = *(const unsigned*)(base + (size_t)(g * 8 + j) * HWPIX);
#pragma unroll
            for (int j = 0; j < 8; ++j) {
                int m = g * 8 + j; int q = m >> 5; unsigned sh = (unsigned)(m & 31);
#pragma unroll
                for (int p = 0; p < 4; ++p)
                    w[q][p] |= ((v[j] >> (8 * p)) & 1u) << sh;
            }
        }
#pragma unroll
        for (int p = 0; p < 4; ++p) {
            uint4 o; o.x = w[0][p]; o.y = w[1][p]; o.z = w[2][p]; o.w = w[3][p];
            *(uint4*)(maskbits + (size_t)(pix0 + p) * 4) = o;
        }
        return;
    }
    // int32 / f32: nonzero test on raw dword is valid for both.
    int wave_id = bid * 4 + (t >> 6);
    int lane = t & 63;
    const unsigned* r32 = (const unsigned*)raw;
    size_t dbase = (size_t)wave_id * 4096;
    for (int b = 0; b < 8; ++b) {            // 8 batches x 8 groups of 64 dwords (2KB/batch)
        unsigned v[8];
#pragma unroll
        for (int j = 0; j < 8; ++j)
            v[j] = r32[dbase + (size_t)(b * 8 + j) * 64 + lane];
        unsigned long long mine = 0;
#pragma unroll
        for (int j = 0; j < 8; ++j) {
            unsigned long long bal = __ballot(v[j] != 0u);
            if (lane == j) mine = bal;       // lane j keeps group j's word
        }
        if (lane < 8)                        // 64B contiguous store
            bitmap64[(size_t)wave_id * 64 + b * 8 + lane] = mine;
    }
}

// ========== Node B: ballot bit-transpose (bids 0..255) || FPS (256..383) ==========
// For (pixel-group pg of 64 px, mask-half h): lane l loads bitmap64[(h*64+l)*4096+pg]
// (4MB, LLC-hot). 64 ballots flip the 64x64 bit tile: ballot p's bit l = pixel
// pg*64+p of mask h*64+l -> exactly maskbits words 2h,2h+1 for that pixel.
// 1024 waves x 8 (pg,h) pairs = 8192 = 4096*2 exactly.
__global__ void __launch_bounds__(256) k_transpose_fps(const void* raw,
                                                       const unsigned long long* bitmap64,
                                                       unsigned* maskbits,
                                                       const float* pcds, float* reps,
                                                       int packed) {
    int bid = blockIdx.x;
    int t = threadIdx.x;
    if (bid < 256) {
        if (!packed) return;
        if (detect_mode(raw) == 0) return;   // u8 path already wrote maskbits in node A
        int lane = t & 63;
        int gw = bid * 4 + (t >> 6);
        for (int it = 0; it < 8; ++it) {
            int P  = gw * 8 + it;
            int h  = P & 1;
            int pg = P >> 1;
            unsigned long long w64 = bitmap64[(size_t)(h * 64 + lane) * 4096 + pg];
            unsigned long long mine = 0;
#pragma unroll
            for (int p = 0; p < 64; ++p) {
                unsigned long long bal = __ballot((int)((w64 >> p) & 1ull));
                if (p == lane) mine = bal;   // lane p keeps pixel pg*64+p's word pair
            }
            int pix = pg * 64 + lane;
            uint2 o; o.x = (unsigned)mine; o.y = (unsigned)(mine >> 32);
            *(uint2*)(maskbits + (size_t)pix * 4 + h * 2) = o;
        }
        return;
    }
    // ---- FPS role: 128 blocks x 4 waves = 512 superpoints (runs regardless of packed) ----
    fps_wave(pcds, reps, (bid - 256) * 4 + (t >> 6), t & 63);
}

// ========== Node C: counts + feats fused (512 blocks x 512 threads)  [R15 proven] ==========
__global__ void __launch_bounds__(PPS) k_counts_feats(const int* mapping, const unsigned* maskbits,
                                                      const void* raw, int packed,
                                                      const float* feas,
                                                      int* counts, unsigned* contrib, float* feats) {
    int s = blockIdx.x;
    int t = threadIdx.x;
    if (t < 4) contrib[s * 4 + t] = 0u;   // zeroed here; k_topk (later node) atomicOrs
    __shared__ int cnt[NMSK];
    __shared__ float fpart[16][FDIM];
    if (t < NMSK) cnt[t] = 0;
    int mode = 0;
    if (!packed) mode = detect_mode(raw);   // has its own __syncthreads
    __syncthreads();
    int i = s * PPS + t;
    int4 mp = ((const int4*)mapping)[i];
    int y = min(max(mp.y, 0), HH - 1);
    int x = min(max(mp.z, 0), WW - 1);
    bool vis = (mp.w == 1);
    unsigned w0 = 0, w1 = 0, w2 = 0, w3 = 0;
    if (vis) {
        if (packed) {
            uint4 v = *((const uint4*)(maskbits + (size_t)(y * WW + x) * 4));
            w0 = v.x; w1 = v.y; w2 = v.z; w3 = v.w;
        } else {
            long long pix = (long long)y * WW + x;
            for (int m = 0; m < NMSK; ++m) {
                unsigned v = mask_val(raw, (long long)m * HWPIX + pix, mode);
                if (m < 32)       w0 |= v << m;
                else if (m < 64)  w1 |= v << (m - 32);
                else if (m < 96)  w2 |= v << (m - 64);
                else              w3 |= v << (m - 96);
            }
        }
    }
    int lane = t & 63;
    unsigned ww[4] = { w0, w1, w2, w3 };
#pragma unroll
    for (int m = 0; m < NMSK; ++m) {
        unsigned bit = (ww[m >> 5] >> (m & 31)) & 1u;
        unsigned long long bal = __ballot((int)bit);
        if (lane == 0) atomicAdd(&cnt[m], (int)__popcll(bal));
    }
    // ---- feats: dim d = t&31, point-group g = t>>5 (16 groups x 32 points) ----
    {
        int g = t >> 5, d = t & 31;
        const float* fb = feas + (size_t)s * PPS * FDIM;
        float acc = 0.0f;
#pragma unroll 8
        for (int it = 0; it < 32; ++it) acc += fb[(g + 16 * it) * FDIM + d];
        fpart[g][d] = acc;
    }
    __syncthreads();
    if (t < NMSK) counts[s * NMSK + t] = cnt[t];
    if (t < FDIM) {
        float sum = 0.0f;
#pragma unroll
        for (int q = 0; q < 16; ++q) sum += fpart[q][t];
        float f = sum / 512.0f;   // /(P+1e-6) == /512.0f in fp32
        float sq = f * f;
#pragma unroll
        for (int off = 16; off >= 1; off >>= 1) sq += __shfl_xor(sq, off);
        feats[s * FDIM + t] = f / fmaxf(sqrtf(sq), 1e-12f);
    }
}

// ========== Node D: stable per-mask top-k -> contrib bits + frac_kept ==========
__global__ void __launch_bounds__(SPTS) k_topk(const int* counts, unsigned* contrib, float* frac_kept) {
    int m = blockIdx.x;   // mask id
    int s = threadIdx.x;  // superpoint id
    __shared__ int cl[SPTS];
    cl[s] = counts[s * NMSK + m];
    __syncthreads();
    int c = cl[s];
    int rank = 0;
    for (int s2 = 0; s2 < SPTS; ++s2) {
        int c2 = cl[s2];
        rank += (c2 > c || (c2 == c && s2 < s)) ? 1 : 0;
    }
    bool sel = (rank < TOPK_SEL);
    float frac = (float)c / 512.0f;   // counts / (P + 1e-6) == counts / 512.0f in fp32
    frac_kept[s * NMSK + m] = sel ? frac : 0.0f;
    if (sel && frac >= 0.2f)
        atomicOr(&contrib[s * 4 + (m >> 5)], 1u << (m & 31));
}

// ========== Node E: base adjacency + IoU/sim modulation + confidence ==========
__global__ void __launch_bounds__(256) k_adjmod(const float* reps, const unsigned* contrib,
                                                const float* feats, const float* frac_kept,
                                                const float* sam, float* out) {
    if (blockIdx.x >= (SPTS * SPTS) / 256) {
        int s = (blockIdx.x - (SPTS * SPTS) / 256) * 256 + threadIdx.x;
        if (s < SPTS) {
            float sw = 0.0f, sf = 0.0f;
            for (int m = 0; m < NMSK; ++m) {
                float fk = frac_kept[s * NMSK + m];
                sw += fk * sam[m];
                sf += fk;
            }
            out[(size_t)SPTS * SPTS + s] = fmaxf(sw / (sf + 1e-6f), 0.0f);
        }
        return;
    }
    int idx = blockIdx.x * blockDim.x + threadIdx.x;
    int i = idx >> 9, j = idx & 511;
    __shared__ float ri[KFPS * 3];
    __shared__ float sqi[KFPS];
    if (threadIdx.x < KFPS * 3) ri[threadIdx.x] = reps[(size_t)i * KFPS * 3 + threadIdx.x];
    __syncthreads();
    if (threadIdx.x < KFPS) {
        float X = ri[threadIdx.x * 3], Y = ri[threadIdx.x * 3 + 1], Z = ri[threadIdx.x * 3 + 2];
        sqi[threadIdx.x] = X * X + Y * Y + Z * Z;
    }
    __syncthreads();
    float rjx[KFPS], rjy[KFPS], rjz[KFPS], sqj[KFPS];
    const float* rp = reps + (size_t)j * KFPS * 3;
#pragma unroll
    for (int b = 0; b < KFPS; ++b) {
        float X = rp[b * 3], Y = rp[b * 3 + 1], Z = rp[b * 3 + 2];
        rjx[b] = X; rjy[b] = Y; rjz[b] = Z;
        sqj[b] = X * X + Y * Y + Z * Z;
    }
    float mn = 1e30f;
#pragma unroll
    for (int a = 0; a < KFPS; ++a) {
        float ax = ri[a * 3], ay = ri[a * 3 + 1], az = ri[a * 3 + 2];
        float sa = sqi[a];
#pragma unroll
        for (int b = 0; b < KFPS; ++b) {
            float dot = ax * rjx[b] + ay * rjy[b] + az * rjz[b];
            float d2 = (sa + sqj[b]) - 2.0f * dot;   // mirror reference formula
            mn = fminf(mn, d2);
        }
    }
    float dmin = sqrtf(fmaxf(mn, 1e-12f));
    float a = (dmin < 0.2f && i != j) ? expf(-dmin) : 0.0f;
    if (a > 0.0f) {
        uint4 c4i = *((const uint4*)(contrib + (size_t)i * 4));
        uint4 c4j = *((const uint4*)(contrib + (size_t)j * 4));
        unsigned cia[4] = { c4i.x, c4i.y, c4i.z, c4i.w };
        unsigned cja[4] = { c4j.x, c4j.y, c4j.z, c4j.w };
        int taken = 0, inter = 0, uni = 0;
#pragma unroll
        for (int w = 0; w < 4; ++w) {
            unsigned u = cia[w] | cja[w];
            unsigned both = cia[w] & cja[w];
            while (u && taken < NMASK_TOP) {
                unsigned bit = u & (~u + 1u);  // lowest set bit -> ascending index order
                uni++;
                if (both & bit) inter++;
                u ^= bit; taken++;
            }
        }
        float overlap = (float)inter / ((float)uni + 1e-6f);
        const float* fi = feats + (size_t)i * FDIM;
        const float* fj = feats + (size_t)j * FDIM;
        float dot = 0.0f;
#pragma unroll
        for (int d = 0; d < FDIM; ++d) dot += fi[d] * fj[d];
        float sim = (dot + 1.0f) / 2.0f;
        sim = fminf(fmaxf(sim, 0.0f), 1.0f);
        if (sim < 0.5f) sim = 1.0f;
        a = fmaxf(overlap * sim, a);
    }
    out[idx] = a;
}

extern "C" void kernel_launch(void* const* d_in, const int* in_sizes, int n_in,
                              void* d_out, int out_size, void* d_ws, size_t ws_size,
                              hipStream_t stream) {
    const float* pcds    = (const float*)d_in[0];
    // d_in[1] = spt_labels (unused: superpoints are contiguous groups of P)
    const void*  masks   = d_in[2];
    const int*   mapping = (const int*)d_in[3];
    const float* sam     = (const float*)d_in[4];
    const float* feas    = (const float*)d_in[5];
    float* out = (float*)d_out;

    char* ws = (char*)d_ws;
    size_t off = 0;
    auto take = [&](size_t bytes) -> void* {
        void* p = ws + off;
        off += (bytes + 255) & ~(size_t)255;
        return p;
    };
    float*    reps      = (float*)take((size_t)SPTS * KFPS * 3 * sizeof(float));
    int*      counts    = (int*)take((size_t)SPTS * NMSK * sizeof(int));
    unsigned* contrib   = (unsigned*)take((size_t)SPTS * 4 * sizeof(unsigned));
    float*    frac_kept = (float*)take((size_t)SPTS * NMSK * sizeof(float));
    float*    feats     = (float*)take((size_t)SPTS * FDIM * sizeof(float));
    unsigned* maskbits  = (unsigned*)take((size_t)HWPIX * 4 * sizeof(unsigned));
    unsigned long long* bitmap64 =
        (unsigned long long*)take((size_t)(NMSK * (HWPIX / 64)) * sizeof(unsigned long long));
    size_t need_packed = off;
    int packed = (ws_size >= need_packed) ? 1 : 0;

    // Node A: linear ballot-bitpack of the mask array (7TB/s-class sequential read)
    if (packed)
        k_bitpack<<<2048, 256, 0, stream>>>(masks, maskbits, bitmap64);
    // Node B: 64x64 ballot bit-transpose (LLC-hot) || FPS
    k_transpose_fps<<<384, 256, 0, stream>>>(masks, bitmap64, maskbits, pcds, reps, packed);
    // Node C: coverage counts + superpoint features
    k_counts_feats<<<SPTS, PPS, 0, stream>>>(mapping, maskbits, masks, packed, feas,
                                             counts, contrib, feats);
    // Node D: stable per-mask top-k
    k_topk<<<NMSK, SPTS, 0, stream>>>(counts, contrib, frac_kept);
    // Node E: adjacency + modulation + confidence
    k_adjmod<<<(SPTS * SPTS) / 256 + 2, 256, 0, stream>>>(reps, contrib, feats, frac_kept, sam, out);
}

// Round 18
// 70.262 us; speedup vs baseline: 1.2163x; 1.2163x over previous
//
#include <hip/hip_runtime.h>
#include <cstddef>
#include <cstdint>

#define SPTS 512
#define PPS  512
#define KFPS 10
#define NMSK 128
#define HH 512
#define WW 512
#define HWPIX (HH*WW)
#define FDIM 32
#define TOPK_SEL 10
#define NMASK_TOP 5

// ---------- mask dtype handling (u8 / int32 / float32) ----------
__device__ __forceinline__ unsigned mask_val(const void* raw, long long idx, int mode) {
    if (mode == 0) return ((const unsigned char*)raw)[idx] ? 1u : 0u;
    if (mode == 1) return ((const int*)raw)[idx] ? 1u : 0u;
    return (((const float*)raw)[idx] != 0.0f) ? 1u : 0u;
}

// In-block mask dtype detection from the first 4096 bytes (L2-hot after block 0).
// u8 bool: nonzero bytes at offsets %4==1. f32 0/1: nonzero at %4∈{2,3}. int32: %4==0 only.
__device__ __forceinline__ int detect_mode(const void* raw) {
    __shared__ int s_any1, s_any23;
    if (threadIdx.x == 0) { s_any1 = 0; s_any23 = 0; }
    __syncthreads();
    if (threadIdx.x < 256) {
        uint4 w = ((const uint4*)raw)[threadIdx.x];
        unsigned b1  = (w.x >> 8 | w.y >> 8 | w.z >> 8 | w.w >> 8) & 0xFFu;
        unsigned b23 = ((w.x >> 16) | (w.y >> 16) | (w.z >> 16) | (w.w >> 16)) & 0xFFFFu;
        if (b1)  atomicOr(&s_any1, 1);
        if (b23) atomicOr(&s_any23, 1);
    }
    __syncthreads();
    return s_any1 ? 0 : (s_any23 ? 2 : 1);
}

// ---------- wave-level FPS for superpoint s (one 64-lane wave, no block barriers) ----------
__device__ __forceinline__ void fps_wave(const float* pcds, float* reps, int s, int lane) {
    const float* base = pcds + (size_t)s * PPS * 3;
    float px_[8], py_[8], pz_[8];
#pragma unroll
    for (int k = 0; k < 8; ++k) {
        int p = lane + 64 * k;
        px_[k] = base[p * 3 + 0];
        py_[k] = base[p * 3 + 1];
        pz_[k] = base[p * 3 + 2];
    }
    float ax = __shfl(px_[0], 0), ay = __shfl(py_[0], 0), az = __shfl(pz_[0], 0);
    float dist[8];
#pragma unroll
    for (int k = 0; k < 8; ++k) {
        float dx = px_[k] - ax, dy = py_[k] - ay, dz = pz_[k] - az;
        dist[k] = sqrtf(dx * dx + dy * dy + dz * dz);
    }
    if (lane == 0) {
        reps[((size_t)s * KFPS + 0) * 3 + 0] = ax;
        reps[((size_t)s * KFPS + 0) * 3 + 1] = ay;
        reps[((size_t)s * KFPS + 0) * 3 + 2] = az;
    }
    for (int kk = 1; kk < KFPS; ++kk) {
        float bv = dist[0]; int bk = 0;
#pragma unroll
        for (int k = 1; k < 8; ++k)
            if (dist[k] > bv) { bv = dist[k]; bk = k; }
        float v = bv; int pidx = lane + 64 * bk;
        // wave argmax; tie -> lower global point index (matches jnp.argmax)
#pragma unroll
        for (int off = 1; off < 64; off <<= 1) {
            float ov = __shfl_xor(v, off);
            int   op = __shfl_xor(pidx, off);
            if (ov > v || (ov == v && op < pidx)) { v = ov; pidx = op; }
        }
        int owner = pidx & 63, slot = pidx >> 6;
        float sx = px_[0], sy = py_[0], sz = pz_[0];
#pragma unroll
        for (int j = 1; j < 8; ++j)
            if (slot == j) { sx = px_[j]; sy = py_[j]; sz = pz_[j]; }
        sx = __shfl(sx, owner); sy = __shfl(sy, owner); sz = __shfl(sz, owner);
        if (lane == 0) {
            reps[((size_t)s * KFPS + kk) * 3 + 0] = sx;
            reps[((size_t)s * KFPS + kk) * 3 + 1] = sy;
            reps[((size_t)s * KFPS + kk) * 3 + 2] = sz;
        }
#pragma unroll
        for (int k = 0; k < 8; ++k) {
            float dx = px_[k] - sx, dy = py_[k] - sy, dz = pz_[k] - sz;
            float d = sqrtf(dx * dx + dy * dy + dz * dz);
            dist[k] = fminf(dist[k], d);
        }
    }
}

// ========== Node 1: repack (bids 0..255) || FPS (256..383)  [R15: best measured] ==========
// Wide-chunk repack: 4 px/thread x all 128 masks. Per mask the whole block reads
// 4KB CONTIGUOUS (256 thr x uint4) -> amortizes DRAM page activation 4x vs 1KB
// chunks. Explicit 8-deep uint4 batching keeps 8KB/wave in flight (32KB/CU at
// 4 waves/CU >> 15KB Little's-law need).
//   pix0 = bid*1024 + t*4 <= 262140. Max read dword = 127*HWPIX + 262140+3
//   = NMSK*HWPIX-1 (in bounds). Store 64B contiguous/thread; max elem 1048575.
__global__ void __launch_bounds__(256) k_repack_fps(const void* raw, unsigned* maskbits,
                                                    const float* pcds, float* reps) {
    int bid = blockIdx.x;
    int t = threadIdx.x;
    if (bid < 256) {
        int mode = detect_mode(raw);
        int pix0 = bid * 1024 + t * 4;
        unsigned w[4][4] = {};               // w[q][p]: masks [32q,32q+32) for pixel p
        if (mode == 0) {
            const unsigned char* base = (const unsigned char*)raw + pix0;
            for (int g = 0; g < 16; ++g) {   // 16 groups x 8 masks, batched loads
                unsigned v[8];
#pragma unroll
                for (int j = 0; j < 8; ++j)
                    v[j] = *(const unsigned*)(base + (size_t)(g * 8 + j) * HWPIX);
#pragma unroll
                for (int j = 0; j < 8; ++j) {
                    int m = g * 8 + j; int q = m >> 5; unsigned sh = (unsigned)(m & 31);
#pragma unroll
                    for (int p = 0; p < 4; ++p)
                        w[q][p] |= ((v[j] >> (8 * p)) & 1u) << sh;
                }
            }
        } else {
            const unsigned* basep = (const unsigned*)raw + pix0;
            for (int g = 0; g < 16; ++g) {   // 16 groups x 8 masks, batched uint4 loads
                uint4 v[8];
#pragma unroll
                for (int j = 0; j < 8; ++j)
                    v[j] = *(const uint4*)(basep + (size_t)(g * 8 + j) * HWPIX);
#pragma unroll
                for (int j = 0; j < 8; ++j) {
                    int m = g * 8 + j; int q = m >> 5; unsigned sh = (unsigned)(m & 31);
                    w[q][0] |= (unsigned)(v[j].x != 0u) << sh;
                    w[q][1] |= (unsigned)(v[j].y != 0u) << sh;
                    w[q][2] |= (unsigned)(v[j].z != 0u) << sh;
                    w[q][3] |= (unsigned)(v[j].w != 0u) << sh;
                }
            }
        }
#pragma unroll
        for (int p = 0; p < 4; ++p) {        // 64B contiguous per thread
            uint4 o; o.x = w[0][p]; o.y = w[1][p]; o.z = w[2][p]; o.w = w[3][p];
            *(uint4*)(maskbits + (size_t)(pix0 + p) * 4) = o;
        }
        return;
    }
    // ---- FPS role: 128 blocks x 4 waves = 512 superpoints ----
    fps_wave(pcds, reps, (bid - 256) * 4 + (t >> 6), t & 63);
}

// ========== Node 2: counts + feats fused (512 blocks x 512 threads) ==========
__global__ void __launch_bounds__(PPS) k_counts_feats(const int* mapping, const unsigned* maskbits,
                                                      const void* raw, int packed,
                                                      const float* feas,
                                                      int* counts, unsigned* contrib, float* feats) {
    int s = blockIdx.x;
    int t = threadIdx.x;
    if (t < 4) contrib[s * 4 + t] = 0u;   // zeroed here; k_topk (later node) atomicOrs
    __shared__ int cnt[NMSK];
    __shared__ float fpart[16][FDIM];
    if (t < NMSK) cnt[t] = 0;
    int mode = 0;
    if (!packed) mode = detect_mode(raw);   // has its own __syncthreads
    __syncthreads();
    int i = s * PPS + t;
    int4 mp = ((const int4*)mapping)[i];
    int y = min(max(mp.y, 0), HH - 1);
    int x = min(max(mp.z, 0), WW - 1);
    bool vis = (mp.w == 1);
    unsigned w0 = 0, w1 = 0, w2 = 0, w3 = 0;
    if (vis) {
        if (packed) {
            uint4 v = *((const uint4*)(maskbits + (size_t)(y * WW + x) * 4));
            w0 = v.x; w1 = v.y; w2 = v.z; w3 = v.w;
        } else {
            long long pix = (long long)y * WW + x;
            for (int m = 0; m < NMSK; ++m) {
                unsigned v = mask_val(raw, (long long)m * HWPIX + pix, mode);
                if (m < 32)       w0 |= v << m;
                else if (m < 64)  w1 |= v << (m - 32);
                else if (m < 96)  w2 |= v << (m - 64);
                else              w3 |= v << (m - 96);
            }
        }
    }
    int lane = t & 63;
    unsigned ww[4] = { w0, w1, w2, w3 };
#pragma unroll
    for (int m = 0; m < NMSK; ++m) {
        unsigned bit = (ww[m >> 5] >> (m & 31)) & 1u;
        unsigned long long bal = __ballot((int)bit);
        if (lane == 0) atomicAdd(&cnt[m], (int)__popcll(bal));
    }
    // ---- feats: dim d = t&31, point-group g = t>>5 (16 groups x 32 points) ----
    {
        int g = t >> 5, d = t & 31;
        const float* fb = feas + (size_t)s * PPS * FDIM;
        float acc = 0.0f;
#pragma unroll 8
        for (int it = 0; it < 32; ++it) acc += fb[(g + 16 * it) * FDIM + d];
        fpart[g][d] = acc;
    }
    __syncthreads();
    if (t < NMSK) counts[s * NMSK + t] = cnt[t];
    if (t < FDIM) {
        float sum = 0.0f;
#pragma unroll
        for (int q = 0; q < 16; ++q) sum += fpart[q][t];
        float f = sum / 512.0f;   // /(P+1e-6) == /512.0f in fp32
        float sq = f * f;
#pragma unroll
        for (int off = 16; off >= 1; off >>= 1) sq += __shfl_xor(sq, off);
        feats[s * FDIM + t] = f / fmaxf(sqrtf(sq), 1e-12f);
    }
}

// ========== Node 3: stable per-mask top-k -> contrib bits + frac_kept ==========
__global__ void __launch_bounds__(SPTS) k_topk(const int* counts, unsigned* contrib, float* frac_kept) {
    int m = blockIdx.x;   // mask id
    int s = threadIdx.x;  // superpoint id
    __shared__ int cl[SPTS];
    cl[s] = counts[s * NMSK + m];
    __syncthreads();
    int c = cl[s];
    int rank = 0;
    for (int s2 = 0; s2 < SPTS; ++s2) {
        int c2 = cl[s2];
        rank += (c2 > c || (c2 == c && s2 < s)) ? 1 : 0;
    }
    bool sel = (rank < TOPK_SEL);
    float frac = (float)c / 512.0f;   // counts / (P + 1e-6) == counts / 512.0f in fp32
    frac_kept[s * NMSK + m] = sel ? frac : 0.0f;
    if (sel && frac >= 0.2f)
        atomicOr(&contrib[s * 4 + (m >> 5)], 1u << (m & 31));
}

// ========== Node 4: base adjacency + IoU/sim modulation + confidence ==========
__global__ void __launch_bounds__(256) k_adjmod(const float* reps, const unsigned* contrib,
                                                const float* feats, const float* frac_kept,
                                                const float* sam, float* out) {
    if (blockIdx.x >= (SPTS * SPTS) / 256) {
        int s = (blockIdx.x - (SPTS * SPTS) / 256) * 256 + threadIdx.x;
        if (s < SPTS) {
            float sw = 0.0f, sf = 0.0f;
            for (int m = 0; m < NMSK; ++m) {
                float fk = frac_kept[s * NMSK + m];
                sw += fk * sam[m];
                sf += fk;
            }
            out[(size_t)SPTS * SPTS + s] = fmaxf(sw / (sf + 1e-6f), 0.0f);
        }
        return;
    }
    int idx = blockIdx.x * blockDim.x + threadIdx.x;
    int i = idx >> 9, j = idx & 511;
    __shared__ float ri[KFPS * 3];
    __shared__ float sqi[KFPS];
    if (threadIdx.x < KFPS * 3) ri[threadIdx.x] = reps[(size_t)i * KFPS * 3 + threadIdx.x];
    __syncthreads();
    if (threadIdx.x < KFPS) {
        float X = ri[threadIdx.x * 3], Y = ri[threadIdx.x * 3 + 1], Z = ri[threadIdx.x * 3 + 2];
        sqi[threadIdx.x] = X * X + Y * Y + Z * Z;
    }
    __syncthreads();
    float rjx[KFPS], rjy[KFPS], rjz[KFPS], sqj[KFPS];
    const float* rp = reps + (size_t)j * KFPS * 3;
#pragma unroll
    for (int b = 0; b < KFPS; ++b) {
        float X = rp[b * 3], Y = rp[b * 3 + 1], Z = rp[b * 3 + 2];
        rjx[b] = X; rjy[b] = Y; rjz[b] = Z;
        sqj[b] = X * X + Y * Y + Z * Z;
    }
    float mn = 1e30f;
#pragma unroll
    for (int a = 0; a < KFPS; ++a) {
        float ax = ri[a * 3], ay = ri[a * 3 + 1], az = ri[a * 3 + 2];
        float sa = sqi[a];
#pragma unroll
        for (int b = 0; b < KFPS; ++b) {
            float dot = ax * rjx[b] + ay * rjy[b] + az * rjz[b];
            float d2 = (sa + sqj[b]) - 2.0f * dot;   // mirror reference formula
            mn = fminf(mn, d2);
        }
    }
    float dmin = sqrtf(fmaxf(mn, 1e-12f));
    float a = (dmin < 0.2f && i != j) ? expf(-dmin) : 0.0f;
    if (a > 0.0f) {
        uint4 c4i = *((const uint4*)(contrib + (size_t)i * 4));
        uint4 c4j = *((const uint4*)(contrib + (size_t)j * 4));
        unsigned cia[4] = { c4i.x, c4i.y, c4i.z, c4i.w };
        unsigned cja[4] = { c4j.x, c4j.y, c4j.z, c4j.w };
        int taken = 0, inter = 0, uni = 0;
#pragma unroll
        for (int w = 0; w < 4; ++w) {
            unsigned u = cia[w] | cja[w];
            unsigned both = cia[w] & cja[w];
            while (u && taken < NMASK_TOP) {
                unsigned bit = u & (~u + 1u);  // lowest set bit -> ascending index order
                uni++;
                if (both & bit) inter++;
                u ^= bit; taken++;
            }
        }
        float overlap = (float)inter / ((float)uni + 1e-6f);
        const float* fi = feats + (size_t)i * FDIM;
        const float* fj = feats + (size_t)j * FDIM;
        float dot = 0.0f;
#pragma unroll
        for (int d = 0; d < FDIM; ++d) dot += fi[d] * fj[d];
        float sim = (dot + 1.0f) / 2.0f;
        sim = fminf(fmaxf(sim, 0.0f), 1.0f);
        if (sim < 0.5f) sim = 1.0f;
        a = fmaxf(overlap * sim, a);
    }
    out[idx] = a;
}

extern "C" void kernel_launch(void* const* d_in, const int* in_sizes, int n_in,
                              void* d_out, int out_size, void* d_ws, size_t ws_size,
                              hipStream_t stream) {
    const float* pcds    = (const float*)d_in[0];
    // d_in[1] = spt_labels (unused: superpoints are contiguous groups of P)
    const void*  masks   = d_in[2];
    const int*   mapping = (const int*)d_in[3];
    const float* sam     = (const float*)d_in[4];
    const float* feas    = (const float*)d_in[5];
    float* out = (float*)d_out;

    char* ws = (char*)d_ws;
    size_t off = 0;
    auto take = [&](size_t bytes) -> void* {
        void* p = ws + off;
        off += (bytes + 255) & ~(size_t)255;
        return p;
    };
    float*    reps      = (float*)take((size_t)SPTS * KFPS * 3 * sizeof(float));
    int*      counts    = (int*)take((size_t)SPTS * NMSK * sizeof(int));
    unsigned* contrib   = (unsigned*)take((size_t)SPTS * 4 * sizeof(unsigned));
    float*    frac_kept = (float*)take((size_t)SPTS * NMSK * sizeof(float));
    float*    feats     = (float*)take((size_t)SPTS * FDIM * sizeof(float));
    unsigned* maskbits  = (unsigned*)take((size_t)HWPIX * 4 * sizeof(unsigned));
    size_t need_packed = off;
    int packed = (ws_size >= need_packed) ? 1 : 0;

    // Node 1: repack (4KB-chunk streams + 8-deep batched loads) || FPS
    k_repack_fps<<<384, 256, 0, stream>>>(masks, maskbits, pcds, reps);
    // Node 2: coverage counts + superpoint features
    k_counts_feats<<<SPTS, PPS, 0, stream>>>(mapping, maskbits, masks, packed, feas,
                                             counts, contrib, feats);
    // Node 3: stable per-mask top-k
    k_topk<<<NMSK, SPTS, 0, stream>>>(counts, contrib, frac_kept);
    // Node 4: adjacency + modulation + confidence
    k_adjmod<<<(SPTS * SPTS) / 256 + 2, 256, 0, stream>>>(reps, contrib, feats, frac_kept, sam, out);
}